// Round 9
// baseline (376.715 us; speedup 1.0000x reference)
//
#include <hip/hip_runtime.h>
#include <hip/hip_bf16.h>
#include <stdint.h>

typedef __attribute__((ext_vector_type(4))) float f32x4;
typedef __attribute__((ext_vector_type(8))) short s16x8;
typedef unsigned short u16;

// ---------------- helpers ----------------

__device__ __forceinline__ void gl_lds16(const void* g, void* l) {
  __builtin_amdgcn_global_load_lds(
      (const __attribute__((address_space(1))) void*)g,
      (__attribute__((address_space(3))) void*)l,
      16, 0, 0);
}

// Stage 128 rows x 64 bytes (32 bf16) global->LDS.
// LDS linear [row][slot0..3 of 16B]; source pre-swizzled: LDS[row][s] holds
// global chunk s ^ ((row>>1)&3)  (rule #21: inverse-swz source + swz read).
// PERM: LDS row jj holds GLOBAL row sigma(jj) = (jj&64) | 4*(jj&15) | ((jj&63)>>4)
// -> MFMA C-cols become 4-consecutive per lane (coalesced epilogue stores).
template<bool PERM>
__device__ __forceinline__ void stage128x32(const char* g0, int stride, char* lds, int tid) {
  int w = tid >> 6;
#pragma unroll
  for (int h = 0; h < 2; ++h) {
    int c = tid + h * 256;           // chunk 0..511
    int row = c >> 2;
    int srow = row;
    if (PERM) srow = (row & 64) | ((row & 15) << 2) | ((row & 63) >> 4);
    int g = (c & 3) ^ ((row >> 1) & 3);
    gl_lds16(g0 + (size_t)srow * stride + g * 16, lds + h * 4096 + w * 1024);
  }
}

__device__ __forceinline__ s16x8 frag_ld(const char* lds, int row, int g) {
  int slot = g ^ ((row >> 1) & 3);
  return *(const s16x8*)(lds + row * 64 + slot * 16);
}

// One BK=32 step: 8 ds_read_b128 + 16 mfma per wave. Wave owns 64x64 quadrant (wr,wc).
__device__ __forceinline__ void mfma_step(const char* As, const char* Bs,
                                          f32x4 acc[4][4], int lane, int wr, int wc) {
  s16x8 af[4], bf[4];
  int lr = lane & 15, g = lane >> 4;
#pragma unroll
  for (int m = 0; m < 4; ++m) af[m] = frag_ld(As, wr * 64 + m * 16 + lr, g);
#pragma unroll
  for (int n = 0; n < 4; ++n) bf[n] = frag_ld(Bs, wc * 64 + n * 16 + lr, g);
#pragma unroll
  for (int m = 0; m < 4; ++m)
#pragma unroll
    for (int n = 0; n < 4; ++n)
      acc[m][n] = __builtin_amdgcn_mfma_f32_16x16x32_bf16(af[m], bf[n], acc[m][n], 0, 0, 0);
}

__device__ __forceinline__ u16 f2bf(float v) {
  __hip_bfloat16 h = __float2bfloat16(v);
  return *(u16*)&h;
}

// 2-buffer K-loop (32KB LDS -> 5 blocks/CU resident). Stage(k+1) is issued
// right after the barrier, one full compute phase before its vmcnt(0) drain;
// barrier's lgkmcnt(0) guarantees all waves finished reading the buffer
// being overwritten (write-after-read safe).
#define KLOOP2(Ab, Bb, stride, K0, K1, PERMB)                                  \
  {                                                                            \
    stage128x32<false>((Ab) + (K0) * 64, (stride), As[0], tid);                \
    stage128x32<PERMB>((Bb) + (K0) * 64, (stride), Bs[0], tid);                \
    int cur = 0;                                                               \
    for (int ks = (K0); ks < (K1); ++ks) {                                     \
      asm volatile("s_waitcnt lgkmcnt(0) vmcnt(0)\n\ts_barrier" ::: "memory"); \
      if (ks + 1 < (K1)) {                                                     \
        stage128x32<false>((Ab) + (ks + 1) * 64, (stride), As[cur ^ 1], tid);  \
        stage128x32<PERMB>((Bb) + (ks + 1) * 64, (stride), Bs[cur ^ 1], tid);  \
      }                                                                        \
      mfma_step(As[cur], Bs[cur], acc, lane, wr, wc);                          \
      cur ^= 1;                                                                \
    }                                                                          \
  }

// ---------------- kernels ----------------

// Fused prep: x -> out[:, :512] + Xb(bf16); zero out rows>=512 of out[:,512:];
// W -> Wb(bf16); colsum -> 0.
__global__ __launch_bounds__(256) void prep(const float* __restrict__ x,
                                            const float* __restrict__ Wq,
                                            const float* __restrict__ Wk,
                                            const float* __restrict__ Wv,
                                            float* __restrict__ out,
                                            u16* __restrict__ Xb,
                                            u16* __restrict__ Wb,
                                            float* __restrict__ colsum) {
  int bx = blockIdx.x, tid = threadIdx.x;
  if (bx < 64) colsum[(bx << 8) + tid] = 0.f;
  if (bx < 4096) {
    size_t i = ((size_t)bx * 256 + tid) * 8;
    size_t tk = i >> 9;
    int c = (int)(i & 511);
    float4 a = *(const float4*)(x + i);
    float4 b = *(const float4*)(x + i + 4);
    *(float4*)(out + tk * 1024 + c) = a;
    *(float4*)(out + tk * 1024 + c + 4) = b;
    if ((tk & 2047) >= 512) {   // rows that pv split-K accumulates atomically
      float4 z = {0.f, 0.f, 0.f, 0.f};
      *(float4*)(out + tk * 1024 + 512 + c) = z;
      *(float4*)(out + tk * 1024 + 516 + c) = z;
    }
    union { u16 us[8]; uint4 v; } pk;
    pk.us[0] = f2bf(a.x); pk.us[1] = f2bf(a.y); pk.us[2] = f2bf(a.z); pk.us[3] = f2bf(a.w);
    pk.us[4] = f2bf(b.x); pk.us[5] = f2bf(b.y); pk.us[6] = f2bf(b.z); pk.us[7] = f2bf(b.w);
    *(uint4*)(Xb + i) = pk.v;
  } else {
    int t = (bx - 4096) * 256 + tid;        // 0..98303
    int m = t >> 15;
    int off = (t & 32767) * 8;
    const float* W = (m == 0) ? Wq : ((m == 1) ? Wk : Wv);
    union { u16 us[8]; uint4 v; } pk;
#pragma unroll
    for (int k = 0; k < 8; ++k) pk.us[k] = f2bf(W[off + k]);
    *(uint4*)(Wb + (size_t)m * 262144 + off) = pk.v;
  }
}

// Q/K/V fused GEMM: [16384x512] x [1536x512]^T -> Q,K,V bf16 (+bias).
// B staged sigma-permuted: lane owns 4 consecutive out-cols -> 8B packed stores.
__global__ __launch_bounds__(256, 4) void qkv_gemm(const u16* __restrict__ Xb, const u16* __restrict__ Wb,
                                                   const float* __restrict__ bq, const float* __restrict__ bk,
                                                   const float* __restrict__ bv,
                                                   u16* __restrict__ Qb, u16* __restrict__ Kb, u16* __restrict__ Vb) {
  __shared__ __align__(16) char As[2][8192], Bs[2][8192];
  int tid = threadIdx.x, lane = tid & 63, wid = tid >> 6;
  int wr = wid >> 1, wc = wid & 1;
  int bm = blockIdx.x, bn = blockIdx.y;
  const char* Ab = (const char*)(Xb + (size_t)bm * 128 * 512);
  const char* Bb = (const char*)(Wb + (size_t)bn * 128 * 512);
  f32x4 acc[4][4] = {};
  KLOOP2(Ab, Bb, 1024, 0, 16, true);
  int row0 = bm * 128 + wr * 64 + (lane >> 4) * 4;
  int lr = lane & 15;
  int cg0 = bn * 128 + wc * 64 + lr * 4;      // 4-aligned, no 512-straddle
  int sel = cg0 >> 9, nn0 = cg0 & 511;
  const float* bias = (sel == 0) ? bq : ((sel == 1) ? bk : bv);
  u16* O = (sel == 0) ? Qb : ((sel == 1) ? Kb : Vb);
  float4 bb = *(const float4*)(bias + nn0);
#pragma unroll
  for (int m = 0; m < 4; ++m)
#pragma unroll
    for (int r = 0; r < 4; ++r) {
      union { u16 us[4]; uint2 v; } pk;
      pk.us[0] = f2bf(acc[m][0][r] + bb.x);
      pk.us[1] = f2bf(acc[m][1][r] + bb.y);
      pk.us[2] = f2bf(acc[m][2][r] + bb.z);
      pk.us[3] = f2bf(acc[m][3][r] + bb.w);
      *(uint2*)&O[(size_t)(row0 + m * 16 + r) * 512 + nn0] = pk.v;
    }
}

// E = exp(QK^T/sqrt(512)) masked (j<=i), colsum_j += sum_i E_ij.
// XCD-chunked (one batch per XCD); K staged sigma-permuted -> 8B packed E stores.
__global__ __launch_bounds__(256, 4) void scores(const u16* __restrict__ Qb, const u16* __restrict__ Kb,
                                                 u16* __restrict__ E, float* __restrict__ colsum) {
  __shared__ __align__(16) char As[2][8192], Bs[2][8192];
  __shared__ float colred[128];
  int tid = threadIdx.x, lane = tid & 63, wid = tid >> 6;
  int wr = wid >> 1, wc = wid & 1;
  int d = blockIdx.x;
  int id = (d & 7) * 136 + (d >> 3);   // bijective: round-robin -> chunked
  int b = id / 136, t = id - b * 136;
  int bi = (int)((sqrtf(8.f * t + 1.f) - 1.f) * 0.5f);
  while ((bi + 1) * (bi + 2) / 2 <= t) ++bi;
  while (bi * (bi + 1) / 2 > t) --bi;
  int bj = t - bi * (bi + 1) / 2;
  const char* Ab = (const char*)(Qb + ((size_t)b * 2048 + bi * 128) * 512);
  const char* Bb = (const char*)(Kb + ((size_t)b * 2048 + bj * 128) * 512);
  f32x4 acc[4][4] = {};
  KLOOP2(Ab, Bb, 1024, 0, 16, true);
  if (tid < 128) colred[tid] = 0.f;
  __syncthreads();
  const float expc = 1.4426950408889634f / 22.627416997969522f; // log2(e)/sqrt(512)
  int i0 = bi * 128 + wr * 64 + (lane >> 4) * 4;
  int lr = lane & 15;
  int jg0 = bj * 128 + wc * 64 + lr * 4;
  u16* Eb = E + (size_t)b * 2048 * 2048;
  float csum4[4] = {0.f, 0.f, 0.f, 0.f};
#pragma unroll
  for (int m = 0; m < 4; ++m)
#pragma unroll
    for (int r = 0; r < 4; ++r) {
      int ig = i0 + m * 16 + r;
      union { u16 us[4]; uint2 v; } pk;
#pragma unroll
      for (int n = 0; n < 4; ++n) {
        float e = (jg0 + n > ig) ? 0.f : exp2f(acc[m][n][r] * expc);
        pk.us[n] = f2bf(e);
        csum4[n] += e;
      }
      *(uint2*)&Eb[(size_t)ig * 2048 + jg0] = pk.v;
    }
#pragma unroll
  for (int n = 0; n < 4; ++n) {
    float v = csum4[n];
    v += __shfl_xor(v, 16);
    v += __shfl_xor(v, 32);
    if ((lane >> 4) == 0) atomicAdd(&colred[wc * 64 + lr * 4 + n], v);
  }
  __syncthreads();
  if (tid < 128) atomicAdd(&colsum[b * 2048 + bj * 128 + tid], colred[tid]);
}

// Vt[b][n][j] = Vb[b][j][n] / colsum[b][j]  (64x64 tiles)
__global__ __launch_bounds__(256) void vtrans(const u16* __restrict__ Vb, const float* __restrict__ colsum,
                                              u16* __restrict__ Vt) {
  __shared__ u16 tile[64][72];
  __shared__ float scale[64];
  int b = blockIdx.z, j0 = blockIdx.x * 64, n0 = blockIdx.y * 64;
  int t = threadIdx.x;
  if (t < 64) scale[t] = 1.f / colsum[b * 2048 + j0 + t];
#pragma unroll
  for (int p = 0; p < 2; ++p) {
    int c = t + p * 256, r = c >> 3, nf = (c & 7) * 8;
    *(uint4*)&tile[r][nf] = *(const uint4*)(Vb + ((size_t)(b * 2048 + j0 + r)) * 512 + n0 + nf);
  }
  __syncthreads();
#pragma unroll
  for (int p = 0; p < 2; ++p) {
    int c = t + p * 256, n = c >> 3, jf = (c & 7) * 8;
    union { u16 us[8]; uint4 v; } pk;
#pragma unroll
    for (int k = 0; k < 8; ++k) {
      uint32_t bits = ((uint32_t)tile[jf + k][n]) << 16;
      float v; __builtin_memcpy(&v, &bits, 4);
      pk.us[k] = f2bf(v * scale[jf + k]);
    }
    *(uint4*)(Vt + ((size_t)(b * 512 + n0 + n)) * 2048 + j0 + jf) = pk.v;
  }
}

// out[:, 512:] = E @ V'. Split-K: mi>=4 tiles split into 2 K-chunks (max chain
// 32 steps) accumulated via fp32 atomicAdd onto pre-zeroed rows; mi<4 plain
// stores. Vt staged sigma-permuted -> lane owns 4 consecutive cols.
__global__ __launch_bounds__(256, 4) void pv_gemm(const u16* __restrict__ E, const u16* __restrict__ Vt,
                                                  float* __restrict__ out) {
  __shared__ __align__(16) char As[2][8192], Bs[2][8192];
  int tid = threadIdx.x, lane = tid & 63, wid = tid >> 6;
  int wr = wid >> 1, wc = wid & 1;
  int d = blockIdx.x;                  // 896 blocks
  int b = d & 7, slot = d >> 3;        // batch per XCD; slot 0..111
  int nj = slot & 3, u = slot >> 2;    // u 0..27, long chunks dispatched first
  int mi, k0, k1;
  bool split = (u < 24);
  if (split) {
    mi = 15 - (u >> 1);                // 15..4
    int NK = (mi + 1) * 4, h = NK >> 1;
    k0 = (u & 1) ? h : 0;
    k1 = (u & 1) ? NK : h;
  } else {
    mi = 27 - u;                       // 3..0
    k0 = 0; k1 = (mi + 1) * 4;
  }
  const char* Ab = (const char*)(E + ((size_t)b * 2048 + mi * 128) * 2048);
  const char* Bb = (const char*)(Vt + ((size_t)b * 512 + nj * 128) * 2048);
  f32x4 acc[4][4] = {};
  KLOOP2(Ab, Bb, 4096, k0, k1, true);
  int i0 = mi * 128 + wr * 64 + (lane >> 4) * 4;
  int lr = lane & 15;
  int n0 = 512 + nj * 128 + wc * 64 + lr * 4;   // 4 consecutive cols per lane
  float* ob = out + (size_t)b * 2048 * 1024;
#pragma unroll
  for (int m = 0; m < 4; ++m)
#pragma unroll
    for (int r = 0; r < 4; ++r) {
      float* p = &ob[(size_t)(i0 + m * 16 + r) * 1024 + n0];
      if (split) {
        atomicAdd(p + 0, acc[m][0][r]);
        atomicAdd(p + 1, acc[m][1][r]);
        atomicAdd(p + 2, acc[m][2][r]);
        atomicAdd(p + 3, acc[m][3][r]);
      } else {
        float4 v = {acc[m][0][r], acc[m][1][r], acc[m][2][r], acc[m][3][r]};
        *(float4*)p = v;
      }
    }
}

// ---------------- launch ----------------

extern "C" void kernel_launch(void* const* d_in, const int* in_sizes, int n_in,
                              void* d_out, int out_size, void* d_ws, size_t ws_size,
                              hipStream_t stream) {
  const float* x  = (const float*)d_in[0];
  const float* Wq = (const float*)d_in[1];
  const float* bq = (const float*)d_in[2];
  const float* Wk = (const float*)d_in[3];
  const float* bk = (const float*)d_in[4];
  const float* Wv = (const float*)d_in[5];
  const float* bv = (const float*)d_in[6];
  float* out = (float*)d_out;
  char* ws = (char*)d_ws;

  // ws layout (bytes): Xb 16MB | Wb 1.5MB | Qb 16MB | Kb 16MB | Vb 16MB | Vt 16MB | E 64MB | colsum 64KB
  u16* Xb = (u16*)(ws);
  u16* Wb = (u16*)(ws + 16777216);
  u16* Qb = (u16*)(ws + 18350080);
  u16* Kb = (u16*)(ws + 35127296);
  u16* Vb = (u16*)(ws + 51904512);
  u16* Vt = (u16*)(ws + 68681728);
  u16* E  = (u16*)(ws + 85458944);
  float* colsum = (float*)(ws + 152567808);

  prep<<<4480, 256, 0, stream>>>(x, Wq, Wk, Wv, out, Xb, Wb, colsum);
  qkv_gemm<<<dim3(128, 12), 256, 0, stream>>>(Xb, Wb, bq, bk, bv, Qb, Kb, Vb);
  scores<<<1088, 256, 0, stream>>>(Qb, Kb, E, colsum);
  vtrans<<<dim3(32, 8, 8), 256, 0, stream>>>(Vb, colsum, Vt);
  pv_gemm<<<896, 256, 0, stream>>>(E, Vt, out);
}